// Round 2
// baseline (57.008 us; speedup 1.0000x reference)
//
#include <hip/hip_runtime.h>

// FrequencyAdaptiveNorm: per-timestep LayerNorm(F=256) + mask-weighted affine.
// x: (B=32, S=4096, F=256) f32; gamma,beta: (3,256) f32; weights: (3,) f32.
//
// Round-2 design:
//  - prep kernel folds softmax(weights) + border masks + gamma/beta into
//    4 region-class tables G[cls][256], B[cls][256] stored in d_ws (8 KB).
//  - main kernel: 2 rows per wave (32 lanes x 8 feats/lane), 5-level
//    butterfly reduce, nontemporal stores so `out` does not evict the
//    L3-resident x between graph replays.

#define S_LEN 4096
#define F_LEN 256
#define EPSV 1e-5f

typedef float f32x4 __attribute__((ext_vector_type(4)));

__global__ void fan_prep(const float* __restrict__ g,
                         const float* __restrict__ b,
                         const float* __restrict__ w,
                         float* __restrict__ tbl)   // [8][256]: G[0..3], B[0..3]
{
    const int f = threadIdx.x;                      // 256 threads, 1 block
    const float l0 = w[0], l1 = w[1], l2 = w[2];
    const float mx = fmaxf(l0, fmaxf(l1, l2));
    const float e0 = expf(l0 - mx), e1 = expf(l1 - mx), e2 = expf(l2 - mx);
    const float inv = 1.0f / (e0 + e1 + e2);
    const float w0 = e0 * inv, w1 = e1 * inv, w2 = e2 * inv;

    const float g0 = g[f], g1 = g[F_LEN + f], g2 = g[2 * F_LEN + f];
    const float b0 = b[f], b1 = b[F_LEN + f], b2 = b[2 * F_LEN + f];

    // class 0: no window valid; 1: ws=5 only; 2: ws=5+10; 3: all three
    tbl[0 * F_LEN + f] = 0.0f;
    tbl[1 * F_LEN + f] = w0 * g0;
    tbl[2 * F_LEN + f] = w0 * g0 + w1 * g1;
    tbl[3 * F_LEN + f] = w0 * g0 + w1 * g1 + w2 * g2;
    tbl[4 * F_LEN + f] = 0.0f;
    tbl[5 * F_LEN + f] = w0 * b0;
    tbl[6 * F_LEN + f] = w0 * b0 + w1 * b1;
    tbl[7 * F_LEN + f] = w0 * b0 + w1 * b1 + w2 * b2;
}

__global__ __launch_bounds__(256) void fan_main(
    const float* __restrict__ x,
    const float* __restrict__ tbl,
    float* __restrict__ out,
    int n_rows)
{
    const int lane = threadIdx.x & 63;
    const int wave = threadIdx.x >> 6;
    const int half = lane & 31;        // lane within 32-lane half-wave
    const int rsel = lane >> 5;        // which of the wave's 2 rows
    const int row  = blockIdx.x * 8 + wave * 2 + rsel;
    if (row >= n_rows) return;

    const int t = row & (S_LEN - 1);
    // region class: valid ranges ws5=[2,4094) ws10=[5,4092) ws20=[10,4087)
    int cls;
    if (t >= 10 && t < 4087)                              cls = 3;
    else if ((t >= 5 && t < 10) || (t >= 4087 && t < 4092)) cls = 2;
    else if ((t >= 2 && t < 5) || (t >= 4092 && t < 4094))  cls = 1;
    else                                                    cls = 0;

    const size_t base = (size_t)row * F_LEN + (size_t)half * 8;
    const f32x4 x0 = *reinterpret_cast<const f32x4*>(x + base);
    const f32x4 x1 = *reinterpret_cast<const f32x4*>(x + base + 4);

    float s  = ((x0.x + x0.y) + (x0.z + x0.w)) + ((x1.x + x1.y) + (x1.z + x1.w));
    float sq = ((x0.x*x0.x + x0.y*x0.y) + (x0.z*x0.z + x0.w*x0.w))
             + ((x1.x*x1.x + x1.y*x1.y) + (x1.z*x1.z + x1.w*x1.w));

    // 5-level butterfly within each 32-lane half (offsets <= 16 never cross)
    #pragma unroll
    for (int off = 16; off >= 1; off >>= 1) {
        s  += __shfl_xor(s,  off);
        sq += __shfl_xor(sq, off);
    }

    const float mean = s * (1.0f / F_LEN);
    const float var  = sq * (1.0f / F_LEN) - mean * mean;
    const float rstd = rsqrtf(var + EPSV);

    const float* Gp = tbl + cls * F_LEN + half * 8;
    const float* Bp = tbl + (4 + cls) * F_LEN + half * 8;
    const f32x4 G0 = *reinterpret_cast<const f32x4*>(Gp);
    const f32x4 G1 = *reinterpret_cast<const f32x4*>(Gp + 4);
    const f32x4 B0 = *reinterpret_cast<const f32x4*>(Bp);
    const f32x4 B1 = *reinterpret_cast<const f32x4*>(Bp + 4);

    f32x4 o0, o1;
    o0.x = (x0.x - mean) * rstd * G0.x + B0.x;
    o0.y = (x0.y - mean) * rstd * G0.y + B0.y;
    o0.z = (x0.z - mean) * rstd * G0.z + B0.z;
    o0.w = (x0.w - mean) * rstd * G0.w + B0.w;
    o1.x = (x1.x - mean) * rstd * G1.x + B1.x;
    o1.y = (x1.y - mean) * rstd * G1.y + B1.y;
    o1.z = (x1.z - mean) * rstd * G1.z + B1.z;
    o1.w = (x1.w - mean) * rstd * G1.w + B1.w;

    // nontemporal: don't let `out` evict the L3-resident x
    __builtin_nontemporal_store(o0, reinterpret_cast<f32x4*>(out + base));
    __builtin_nontemporal_store(o1, reinterpret_cast<f32x4*>(out + base + 4));
}

extern "C" void kernel_launch(void* const* d_in, const int* in_sizes, int n_in,
                              void* d_out, int out_size, void* d_ws, size_t ws_size,
                              hipStream_t stream) {
    const float* x       = (const float*)d_in[0];
    const float* gamma   = (const float*)d_in[1];
    const float* beta    = (const float*)d_in[2];
    const float* weights = (const float*)d_in[3];
    float* out = (float*)d_out;
    float* tbl = (float*)d_ws;                    // 8 KB: G[4][256], B[4][256]

    const int n_rows = out_size / F_LEN;          // B*S = 131072
    const int blocks = (n_rows + 7) / 8;          // 8 rows per 256-thread block

    fan_prep<<<1, 256, 0, stream>>>(gamma, beta, weights, tbl);
    fan_main<<<blocks, 256, 0, stream>>>(x, tbl, out, n_rows);
}

// Round 3
// 46.580 us; speedup vs baseline: 1.2239x; 1.2239x over previous
//
#include <hip/hip_runtime.h>

// FrequencyAdaptiveNorm: per-timestep LayerNorm(F=256) + mask-weighted affine.
// x: (B=32, S=4096, F=256) f32; gamma,beta: (3,256) f32; weights: (3,) f32.
//
// Round-3: exact round-1 structure (single kernel, 1 row/wave, 46 µs) with ONE
// change: nontemporal stores on `out` (write-once data; keep x L3-resident).

#define S_LEN 4096
#define F_LEN 256
#define EPSV 1e-5f

typedef float f32x4 __attribute__((ext_vector_type(4)));

__global__ __launch_bounds__(256) void fan_ln_kernel(
    const float* __restrict__ x,
    const float* __restrict__ gamma,
    const float* __restrict__ beta,
    const float* __restrict__ weights,
    float* __restrict__ out,
    int n_rows)
{
    const int wave = threadIdx.x >> 6;      // 4 waves/block, 1 row/wave
    const int lane = threadIdx.x & 63;      // 64 lanes * float4 = 256 feats
    const int row = blockIdx.x * 4 + wave;
    if (row >= n_rows) return;

    const int t = row & (S_LEN - 1);        // timestep within sequence
    const size_t base = (size_t)row * F_LEN;

    // ---- softmax over the 3 aggregation logits (uniform scalars) ----
    float l0 = weights[0], l1 = weights[1], l2 = weights[2];
    float mx = fmaxf(l0, fmaxf(l1, l2));
    float e0 = expf(l0 - mx), e1 = expf(l1 - mx), e2 = expf(l2 - mx);
    float inv = 1.0f / (e0 + e1 + e2);
    float w0 = e0 * inv, w1 = e1 * inv, w2 = e2 * inv;

    // ---- border masks (valid unfold range per window size) ----
    const float m0 = (t >= 2  && t < 4094) ? w0 : 0.0f;
    const float m1 = (t >= 5  && t < 4092) ? w1 : 0.0f;
    const float m2 = (t >= 10 && t < 4087) ? w2 : 0.0f;

    // ---- load this lane's 4 features ----
    const f32x4 xv = reinterpret_cast<const f32x4*>(x + base)[lane];

    float s  = (xv.x + xv.y) + (xv.z + xv.w);
    float sq = (xv.x*xv.x + xv.y*xv.y) + (xv.z*xv.z + xv.w*xv.w);

    // ---- wave-wide butterfly reduction (64 lanes) ----
    #pragma unroll
    for (int off = 32; off >= 1; off >>= 1) {
        s  += __shfl_xor(s,  off);
        sq += __shfl_xor(sq, off);
    }

    const float mean = s * (1.0f / F_LEN);
    const float var  = sq * (1.0f / F_LEN) - mean * mean;
    const float rstd = rsqrtf(var + EPSV);

    // ---- per-feature fused affine ----
    const f32x4 g0 = reinterpret_cast<const f32x4*>(gamma + 0 * F_LEN)[lane];
    const f32x4 g1 = reinterpret_cast<const f32x4*>(gamma + 1 * F_LEN)[lane];
    const f32x4 g2 = reinterpret_cast<const f32x4*>(gamma + 2 * F_LEN)[lane];
    const f32x4 b0 = reinterpret_cast<const f32x4*>(beta  + 0 * F_LEN)[lane];
    const f32x4 b1 = reinterpret_cast<const f32x4*>(beta  + 1 * F_LEN)[lane];
    const f32x4 b2 = reinterpret_cast<const f32x4*>(beta  + 2 * F_LEN)[lane];

    f32x4 ov;
    {
        float G  = m0*g0.x + m1*g1.x + m2*g2.x;
        float Bv = m0*b0.x + m1*b1.x + m2*b2.x;
        ov.x = (xv.x - mean) * rstd * G + Bv;
        G  = m0*g0.y + m1*g1.y + m2*g2.y;
        Bv = m0*b0.y + m1*b1.y + m2*b2.y;
        ov.y = (xv.y - mean) * rstd * G + Bv;
        G  = m0*g0.z + m1*g1.z + m2*g2.z;
        Bv = m0*b0.z + m1*b1.z + m2*b2.z;
        ov.z = (xv.z - mean) * rstd * G + Bv;
        G  = m0*g0.w + m1*g1.w + m2*g2.w;
        Bv = m0*b0.w + m1*b1.w + m2*b2.w;
        ov.w = (xv.w - mean) * rstd * G + Bv;
    }

    // THE one change vs round 1: nontemporal store (out is never re-read;
    // don't let it evict L3-resident x between graph replays).
    __builtin_nontemporal_store(ov, reinterpret_cast<f32x4*>(out + base) + lane);
}

extern "C" void kernel_launch(void* const* d_in, const int* in_sizes, int n_in,
                              void* d_out, int out_size, void* d_ws, size_t ws_size,
                              hipStream_t stream) {
    const float* x       = (const float*)d_in[0];
    const float* gamma   = (const float*)d_in[1];
    const float* beta    = (const float*)d_in[2];
    const float* weights = (const float*)d_in[3];
    float* out = (float*)d_out;

    const int n_rows = out_size / F_LEN;          // B*S = 131072
    const int blocks = (n_rows + 3) / 4;          // 4 rows per 256-thread block

    fan_ln_kernel<<<blocks, 256, 0, stream>>>(x, gamma, beta, weights, out, n_rows);
}

// Round 4
// 44.134 us; speedup vs baseline: 1.2917x; 1.0554x over previous
//
#include <hip/hip_runtime.h>

// FrequencyAdaptiveNorm: per-timestep LayerNorm(F=256) + mask-weighted affine.
// x: (B=32, S=4096, F=256) f32; gamma,beta: (3,256) f32; weights: (3,) f32.
//
// Round-4: 4 rows per wave. All 4 x-loads issued up front (latency hiding);
// softmax + gamma/beta + interior affine combo hoisted to once per wave.
// Interior rows (4077/4096) use precombined G3/B3; border rows recompute.

#define S_LEN 4096
#define F_LEN 256
#define EPSV 1e-5f
#define RPW 4                       // rows per wave

typedef float f32x4 __attribute__((ext_vector_type(4)));

__global__ __launch_bounds__(256) void fan_ln_kernel(
    const float* __restrict__ x,
    const float* __restrict__ gamma,
    const float* __restrict__ beta,
    const float* __restrict__ weights,
    float* __restrict__ out,
    int n_rows)
{
    const int wave = threadIdx.x >> 6;
    const int lane = threadIdx.x & 63;
    const int row0 = (blockIdx.x * 4 + wave) * RPW;
    if (row0 >= n_rows) return;

    // ---- prefetch all 4 row fragments (64 B/lane in flight) ----
    f32x4 xv0 = reinterpret_cast<const f32x4*>(x + (size_t)(row0 + 0) * F_LEN)[lane];
    f32x4 xv1 = reinterpret_cast<const f32x4*>(x + (size_t)(row0 + 1) * F_LEN)[lane];
    f32x4 xv2 = reinterpret_cast<const f32x4*>(x + (size_t)(row0 + 2) * F_LEN)[lane];
    f32x4 xv3 = reinterpret_cast<const f32x4*>(x + (size_t)(row0 + 3) * F_LEN)[lane];

    // ---- once per wave: softmax of the 3 logits ----
    const float l0 = weights[0], l1 = weights[1], l2 = weights[2];
    const float mx = fmaxf(l0, fmaxf(l1, l2));
    const float e0 = expf(l0 - mx), e1 = expf(l1 - mx), e2 = expf(l2 - mx);
    const float inv = 1.0f / (e0 + e1 + e2);
    const float w0 = e0 * inv, w1 = e1 * inv, w2 = e2 * inv;

    // ---- once per wave: gamma/beta + interior combination ----
    const f32x4 g0 = reinterpret_cast<const f32x4*>(gamma + 0 * F_LEN)[lane];
    const f32x4 g1 = reinterpret_cast<const f32x4*>(gamma + 1 * F_LEN)[lane];
    const f32x4 g2 = reinterpret_cast<const f32x4*>(gamma + 2 * F_LEN)[lane];
    const f32x4 b0 = reinterpret_cast<const f32x4*>(beta  + 0 * F_LEN)[lane];
    const f32x4 b1 = reinterpret_cast<const f32x4*>(beta  + 1 * F_LEN)[lane];
    const f32x4 b2 = reinterpret_cast<const f32x4*>(beta  + 2 * F_LEN)[lane];
    const f32x4 G3 = w0 * g0 + w1 * g1 + w2 * g2;   // all-windows-valid combo
    const f32x4 B3 = w0 * b0 + w1 * b1 + w2 * b2;

    #pragma unroll
    for (int r = 0; r < RPW; ++r) {
        const f32x4 xv = (r == 0) ? xv0 : (r == 1) ? xv1 : (r == 2) ? xv2 : xv3;
        const int row = row0 + r;
        const int t = row & (S_LEN - 1);

        float s  = (xv.x + xv.y) + (xv.z + xv.w);
        float sq = (xv.x*xv.x + xv.y*xv.y) + (xv.z*xv.z + xv.w*xv.w);
        #pragma unroll
        for (int off = 32; off >= 1; off >>= 1) {
            s  += __shfl_xor(s,  off);
            sq += __shfl_xor(sq, off);
        }
        const float mean = s * (1.0f / F_LEN);
        const float var  = sq * (1.0f / F_LEN) - mean * mean;
        const float rstd = rsqrtf(var + EPSV);

        f32x4 G, Bv;
        if (t >= 10 && t < 4087) {          // interior: wave-uniform fast path
            G = G3; Bv = B3;
        } else {                            // border: 19 of 4096 timesteps
            const float m0 = (t >= 2  && t < 4094) ? w0 : 0.0f;
            const float m1 = (t >= 5  && t < 4092) ? w1 : 0.0f;
            const float m2 = (t >= 10 && t < 4087) ? w2 : 0.0f;
            G  = m0 * g0 + m1 * g1 + m2 * g2;
            Bv = m0 * b0 + m1 * b1 + m2 * b2;
        }

        f32x4 ov;
        ov.x = (xv.x - mean) * rstd * G.x + Bv.x;
        ov.y = (xv.y - mean) * rstd * G.y + Bv.y;
        ov.z = (xv.z - mean) * rstd * G.z + Bv.z;
        ov.w = (xv.w - mean) * rstd * G.w + Bv.w;

        __builtin_nontemporal_store(
            ov, reinterpret_cast<f32x4*>(out + (size_t)row * F_LEN) + lane);
    }
}

extern "C" void kernel_launch(void* const* d_in, const int* in_sizes, int n_in,
                              void* d_out, int out_size, void* d_ws, size_t ws_size,
                              hipStream_t stream) {
    const float* x       = (const float*)d_in[0];
    const float* gamma   = (const float*)d_in[1];
    const float* beta    = (const float*)d_in[2];
    const float* weights = (const float*)d_in[3];
    float* out = (float*)d_out;

    const int n_rows = out_size / F_LEN;              // B*S = 131072
    const int rows_per_block = 4 * RPW;               // 4 waves x 4 rows
    const int blocks = (n_rows + rows_per_block - 1) / rows_per_block;

    fan_ln_kernel<<<blocks, 256, 0, stream>>>(x, gamma, beta, weights, out, n_rows);
}